// Round 5
// baseline (634.581 us; speedup 1.0000x reference)
//
#include <hip/hip_runtime.h>
#include <stdint.h>

#define DEV static __device__ __forceinline__

typedef __bf16 bf16x8 __attribute__((ext_vector_type(8)));
typedef float f32x4 __attribute__((ext_vector_type(4)));

typedef const __attribute__((address_space(1))) void* as1cp;
typedef __attribute__((address_space(3))) void* as3p;

DEV uint32_t f2bf1(float f) {
  uint32_t u = __builtin_bit_cast(uint32_t, f);
  u += 0x7fffu + ((u >> 16) & 1u);   // RNE
  return u >> 16;
}
DEV uint32_t f2bf2(float lo, float hi) { return f2bf1(lo) | (f2bf1(hi) << 16); }
DEV float bf2f(uint32_t h) { return __builtin_bit_cast(float, h << 16); }

DEV void gll16(const void* g, void* l) {
  __builtin_amdgcn_global_load_lds((as1cp)g, (as3p)l, 16, 0, 0);
}

// ---------------------------------------------------------------------------
// Projection: out = X @ W^T + b  (M=16384, N=256, K=1024), bf16 MFMA.
// BM=128, BN=128, grid 128x2x3 = 768 blocks = 3 blocks/CU. UNCHANGED from R4.
// z=0 -> q (scaled log2(e)/16), z=1 -> k, z=2 -> v TRANSPOSED [b][d][s].
// ---------------------------------------------------------------------------
__global__ __launch_bounds__(256, 3) void proj_kernel(
    const float* __restrict__ xq, const float* __restrict__ xk, const float* __restrict__ xv,
    const float* __restrict__ wq, const float* __restrict__ wk, const float* __restrict__ wv,
    const float* __restrict__ bq, const float* __restrict__ bk, const float* __restrict__ bv,
    uint16_t* __restrict__ qo, uint16_t* __restrict__ ko, uint16_t* __restrict__ vo)
{
  const int z = blockIdx.z;
  const float* X  = (z == 0) ? xq : (z == 1) ? xk : xv;
  const float* W  = (z == 0) ? wq : (z == 1) ? wk : wv;
  const float* Bi = (z == 0) ? bq : (z == 1) ? bk : bv;

  const int tid = threadIdx.x;
  const int lane = tid & 63;
  const int w = tid >> 6;
  const int wm = w >> 1, wn = w & 1;
  const int l15 = lane & 15, g = lane >> 4;
  const int m0 = blockIdx.x * 128;
  const int n0 = blockIdx.y * 128;

  __shared__ uint16_t sA[128 * 64];
  __shared__ uint16_t sB[128 * 64];

  const int am = tid >> 1, ak = (tid & 1) * 32;
  const float* Ap = X + (size_t)(m0 + am) * 1024 + ak;
  const float* Wp = W + (size_t)(n0 + am) * 1024 + ak;

  f32x4 acc[4][4];
  #pragma unroll
  for (int i = 0; i < 4; ++i)
    #pragma unroll
    for (int j = 0; j < 4; ++j) { f32x4 zz = {0.f, 0.f, 0.f, 0.f}; acc[i][j] = zz; }

  float ar[32];
  #pragma unroll
  for (int i = 0; i < 8; ++i) { float4 t = ((const float4*)Ap)[i];
    ar[4*i+0]=t.x; ar[4*i+1]=t.y; ar[4*i+2]=t.z; ar[4*i+3]=t.w; }

  const uint32_t ph = (uint32_t)(am * 128 + ak * 2) ^ ((uint32_t)(am & 7) << 4);

  for (int kt = 0; kt < 16; ++kt) {
    if (kt) __syncthreads();
    #pragma unroll
    for (int c = 0; c < 4; ++c) {
      uint4 p;
      p.x = f2bf2(ar[8*c+0], ar[8*c+1]); p.y = f2bf2(ar[8*c+2], ar[8*c+3]);
      p.z = f2bf2(ar[8*c+4], ar[8*c+5]); p.w = f2bf2(ar[8*c+6], ar[8*c+7]);
      *(uint4*)((char*)sA + (ph ^ (16u * c))) = p;
    }
    {
      float wr[32];
      const float* Wk = Wp + kt * 64;
      #pragma unroll
      for (int i = 0; i < 8; ++i) { float4 t = ((const float4*)Wk)[i];
        wr[4*i+0]=t.x; wr[4*i+1]=t.y; wr[4*i+2]=t.z; wr[4*i+3]=t.w; }
      #pragma unroll
      for (int c = 0; c < 4; ++c) {
        uint4 p;
        p.x = f2bf2(wr[8*c+0], wr[8*c+1]); p.y = f2bf2(wr[8*c+2], wr[8*c+3]);
        p.z = f2bf2(wr[8*c+4], wr[8*c+5]); p.w = f2bf2(wr[8*c+6], wr[8*c+7]);
        *(uint4*)((char*)sB + (ph ^ (16u * c))) = p;
      }
    }
    __syncthreads();
    if (kt < 15) {
      const float* Ap2 = Ap + (kt + 1) * 64;
      #pragma unroll
      for (int i = 0; i < 8; ++i) { float4 t = ((const float4*)Ap2)[i];
        ar[4*i+0]=t.x; ar[4*i+1]=t.y; ar[4*i+2]=t.z; ar[4*i+3]=t.w; }
    }
    #pragma unroll
    for (int ks = 0; ks < 2; ++ks) {
      bf16x8 fa[4], fb[4];
      #pragma unroll
      for (int f = 0; f < 4; ++f) {
        uint32_t row = wm * 64 + 16 * f + l15;
        fa[f] = *(const bf16x8*)((char*)sA + row * 128 +
                 (((uint32_t)(ks * 64 + g * 16)) ^ ((row & 7) << 4)));
      }
      #pragma unroll
      for (int f = 0; f < 4; ++f) {
        uint32_t row = wn * 64 + 16 * f + l15;
        fb[f] = *(const bf16x8*)((char*)sB + row * 128 +
                 (((uint32_t)(ks * 64 + g * 16)) ^ ((row & 7) << 4)));
      }
      #pragma unroll
      for (int fm = 0; fm < 4; ++fm)
        #pragma unroll
        for (int fn = 0; fn < 4; ++fn)
          acc[fm][fn] = __builtin_amdgcn_mfma_f32_16x16x32_bf16(fa[fm], fb[fn], acc[fm][fn], 0, 0, 0);
    }
  }

  #pragma unroll
  for (int fn = 0; fn < 4; ++fn) {
    const int n = n0 + wn * 64 + 16 * fn + l15;
    const float bias = Bi[n];
    #pragma unroll
    for (int fm = 0; fm < 4; ++fm) {
      const int mg = m0 + wm * 64 + 16 * fm + 4 * g;
      if (z == 0) {
        #pragma unroll
        for (int r = 0; r < 4; ++r)
          qo[(size_t)(mg + r) * 256 + n] =
              (uint16_t)f2bf1((acc[fm][fn][r] + bias) * 0.09016844f); // log2(e)/16
      } else if (z == 1) {
        #pragma unroll
        for (int r = 0; r < 4; ++r)
          ko[(size_t)(mg + r) * 256 + n] = (uint16_t)f2bf1(acc[fm][fn][r] + bias);
      } else {
        uint2 pv;
        pv.x = f2bf2(acc[fm][fn][0] + bias, acc[fm][fn][1] + bias);
        pv.y = f2bf2(acc[fm][fn][2] + bias, acc[fm][fn][3] + bias);
        *(uint2*)(vo + (((size_t)(mg >> 12)) << 20) + (((size_t)n) << 12) + (mg & 4095)) = pv;
      }
    }
  }
}

// ---------------------------------------------------------------------------
// Flash attention v4: 512 thr = 2 KV-halves x 4 q-waves (16 rows), KVBLK=32.
// SINGLE-buffered K/V (72KB LDS total -> 2 blocks/CU), gll staging:
//   K [h][32 rows][512B] col-swizzled via pre-swizzled source;
//   V [h][fd 16][g 4][l15 16][16B] -> PV frag read = Vb + fd*1024 + lane*16
//   (lane-linear, conflict-free). P [8 waves][1KB].
// Loop: compute(t); sync; STAGE(t+1); sync.  launch_bounds(512,4) forces
// <=128 regs -> 16 waves/CU. Flash-merge of halves at end (aliases K region).
// ---------------------------------------------------------------------------
__global__ __launch_bounds__(512, 4) void attn_kernel(
    const uint16_t* __restrict__ qg, const uint16_t* __restrict__ kg,
    const uint16_t* __restrict__ vg, float* __restrict__ out)
{
  extern __shared__ char smem[];   // K:[0,32768) V:[32768,65536) P:[65536,73728)

  const int bid = blockIdx.x;
  const int xcd = bid & 7, slot = bid >> 3;
  const int batch = xcd >> 1;                       // batch pinned to XCD pair
  const int q0 = (((xcd & 1) << 5) + slot) * 64;

  const int tid = threadIdx.x;
  const int lane = tid & 63;
  const int w = tid >> 6;
  const int hv = w >> 2;                  // KV half (0: kv 64t..+32, 1: +32..+64)
  const int wq = w & 3;                   // q sub-tile
  const int l15 = lane & 15, g = lane >> 4;
  const size_t rowb = (size_t)batch * 4096;

  bf16x8 qf[8];
  {
    const uint16_t* qp = qg + (rowb + q0 + wq * 16 + l15) * 256;
    #pragma unroll
    for (int ks = 0; ks < 8; ++ks) qf[ks] = *(const bf16x8*)(qp + ks * 32 + g * 8);
  }

  f32x4 o[16];
  #pragma unroll
  for (int i = 0; i < 16; ++i) { f32x4 zz = {0.f, 0.f, 0.f, 0.f}; o[i] = zz; }
  float mrow[4], lrow[4];
  #pragma unroll
  for (int r = 0; r < 4; ++r) { mrow[r] = -1e30f; lrow[r] = 0.f; }

  const char* kgb = (const char*)(kg + rowb * 256);                 // K [s][256]
  const char* vgb = (const char*)(vg + (size_t)batch * 256 * 4096); // V^T [d][4096]

  // staging address precompute (per-thread constants)
  uint32_t ksrc[4], vsrc[4], sdst[4];
  #pragma unroll
  for (int r = 0; r < 4; ++r) {
    uint32_t L = (uint32_t)(r * 512 + tid) * 16;    // linear slot in 32KB region
    sdst[r] = L;
    uint32_t row = (L >> 9) & 31, h = L >> 14;
    ksrc[r] = (32 * h + row) * 512 + ((L & 511) ^ ((row & 7) << 4));
    uint32_t fd = (L >> 10) & 15, g2 = (L >> 8) & 3, lv = (L >> 4) & 15;
    vsrc[r] = (fd * 16 + lv) * 8192 + 64 * h + 16 * g2;
  }

  auto STAGE = [&](int t) {
    const uint32_t kt = (uint32_t)t * 32768;   // 64 kv rows * 512B
    const uint32_t vt = (uint32_t)t * 128;     // 64 kv * 2B
    #pragma unroll
    for (int r = 0; r < 4; ++r) gll16(kgb + kt + ksrc[r], smem + sdst[r]);
    #pragma unroll
    for (int r = 0; r < 4; ++r) gll16(vgb + vt + vsrc[r], smem + 32768 + sdst[r]);
  };

  STAGE(0);
  __syncthreads();                       // vmcnt(0) drained by barrier

  const char* Kb = smem + hv * 16384;
  const char* Vb = smem + 32768 + hv * 16384;
  char* Pw = smem + 65536 + (size_t)w * 1024;

  for (int t = 0; t < 64; ++t) {
    // ---- S = Q K^T : q-row = 4g+r, kv = 16f+l15
    f32x4 s4[2];
    #pragma unroll
    for (int f = 0; f < 2; ++f) { f32x4 zz = {0.f, 0.f, 0.f, 0.f}; s4[f] = zz; }
    #pragma unroll
    for (int ks = 0; ks < 8; ++ks) {
      bf16x8 kf[2];
      #pragma unroll
      for (int f = 0; f < 2; ++f) {
        uint32_t row = 16 * f + l15;
        kf[f] = *(const bf16x8*)(Kb + row * 512 +
                 (((uint32_t)(ks * 64 + g * 16)) ^ ((l15 & 7) << 4)));
      }
      #pragma unroll
      for (int f = 0; f < 2; ++f)
        s4[f] = __builtin_amdgcn_mfma_f32_16x16x32_bf16(qf[ks], kf[f], s4[f], 0, 0, 0);
    }

    // ---- online softmax (exp2 domain) + defer-max (T13, THR=8)
    float mx[4];
    #pragma unroll
    for (int r = 0; r < 4; ++r) {
      float m2 = fmaxf(s4[0][r], s4[1][r]);
      m2 = fmaxf(m2, __shfl_xor(m2, 1, 64));
      m2 = fmaxf(m2, __shfl_xor(m2, 2, 64));
      m2 = fmaxf(m2, __shfl_xor(m2, 4, 64));
      m2 = fmaxf(m2, __shfl_xor(m2, 8, 64));
      mx[r] = m2;
    }
    int stable = (mx[0] <= mrow[0] + 8.f) && (mx[1] <= mrow[1] + 8.f) &&
                 (mx[2] <= mrow[2] + 8.f) && (mx[3] <= mrow[3] + 8.f);
    if (!__all(stable)) {
      float sc[4];
      #pragma unroll
      for (int r = 0; r < 4; ++r) {
        float mn = fmaxf(mrow[r], mx[r]);
        sc[r] = exp2f(mrow[r] - mn);
        mrow[r] = mn;
        lrow[r] *= sc[r];
      }
      #pragma unroll
      for (int j = 0; j < 16; ++j)
        #pragma unroll
        for (int r = 0; r < 4; ++r) o[j][r] *= sc[r];
    }
    float ps[2][4];
    #pragma unroll
    for (int r = 0; r < 4; ++r) {
      float sum = 0.f;
      #pragma unroll
      for (int f = 0; f < 2; ++f) { ps[f][r] = exp2f(s4[f][r] - mrow[r]); sum += ps[f][r]; }
      sum += __shfl_xor(sum, 1, 64);
      sum += __shfl_xor(sum, 2, 64);
      sum += __shfl_xor(sum, 4, 64);
      sum += __shfl_xor(sum, 8, 64);
      lrow[r] += sum;
    }

    // ---- P -> per-wave LDS (row=4g+r, 64B rows, ^(g<<4): 2-way = free)
    #pragma unroll
    for (int f = 0; f < 2; ++f)
      #pragma unroll
      for (int r = 0; r < 4; ++r)
        *(uint16_t*)(Pw + (4 * g + r) * 64 +
            (((uint32_t)(32 * f + 2 * l15)) ^ ((uint32_t)g << 4))) = (uint16_t)f2bf1(ps[f][r]);

    // ---- O += P V (V frag = lane-linear read, conflict-free)
    bf16x8 pa = *(const bf16x8*)(Pw + l15 * 64 + 16 * (g ^ (l15 >> 2)));
    #pragma unroll
    for (int fd = 0; fd < 16; ++fd) {
      bf16x8 vbf = *(const bf16x8*)(Vb + fd * 1024 + lane * 16);
      o[fd] = __builtin_amdgcn_mfma_f32_16x16x32_bf16(pa, vbf, o[fd], 0, 0, 0);
    }

    __syncthreads();                     // all reads of tile t done
    if (t + 1 < 64) STAGE(t + 1);        // DMA next tile into the single buffer
    __syncthreads();                     // drains vmcnt(0): tile t+1 visible
  }

  // ---- merge the two KV halves (flash combine); aliases K/V region (dead)
  float*    mlb = (float*)smem;             // [2][4][64][4] = 8 KB
  uint32_t* ob  = (uint32_t*)(smem + 8192); // [4][32][64]   = 32 KB
  if (hv == 1) {
    #pragma unroll
    for (int r = 0; r < 4; ++r) {
      mlb[((0 * 4 + wq) * 64 + lane) * 4 + r] = mrow[r];
      mlb[((1 * 4 + wq) * 64 + lane) * 4 + r] = lrow[r];
    }
    #pragma unroll
    for (int fd = 0; fd < 16; ++fd)
      #pragma unroll
      for (int p = 0; p < 2; ++p)
        ob[(wq * 32 + fd * 2 + p) * 64 + lane] = f2bf2(o[fd][2 * p], o[fd][2 * p + 1]);
  }
  __syncthreads();
  if (hv == 0) {
    float a[4], b2[4], inv[4];
    #pragma unroll
    for (int r = 0; r < 4; ++r) {
      float mu = mlb[((0 * 4 + wq) * 64 + lane) * 4 + r];
      float lu = mlb[((1 * 4 + wq) * 64 + lane) * 4 + r];
      float mn = fmaxf(mrow[r], mu);
      a[r]  = exp2f(mrow[r] - mn);
      b2[r] = exp2f(mu - mn);
      inv[r] = 1.f / (lrow[r] * a[r] + lu * b2[r]);
    }
    float* op = out + (rowb + q0 + wq * 16) * 256;
    #pragma unroll
    for (int fd = 0; fd < 16; ++fd) {
      #pragma unroll
      for (int p = 0; p < 2; ++p) {
        uint32_t u = ob[(wq * 32 + fd * 2 + p) * 64 + lane];
        float vlo = bf2f(u & 0xffffu), vhi = bf2f(u >> 16);
        int r0 = 2 * p, r1 = 2 * p + 1;
        op[(4 * g + r0) * 256 + 16 * fd + l15] =
            (o[fd][r0] * a[r0] + vlo * b2[r0]) * inv[r0];
        op[(4 * g + r1) * 256 + 16 * fd + l15] =
            (o[fd][r1] * a[r1] + vhi * b2[r1]) * inv[r1];
      }
    }
  }
}

// ---------------------------------------------------------------------------
extern "C" void kernel_launch(void* const* d_in, const int* in_sizes, int n_in,
                              void* d_out, int out_size, void* d_ws, size_t ws_size,
                              hipStream_t stream) {
  const float* xq = (const float*)d_in[0];
  const float* xk = (const float*)d_in[1];
  const float* xv = (const float*)d_in[2];
  // d_in[3] = mask (unused by reference forward)
  const float* wq = (const float*)d_in[4];
  const float* bq = (const float*)d_in[5];
  const float* wk = (const float*)d_in[6];
  const float* bk = (const float*)d_in[7];
  const float* wv = (const float*)d_in[8];
  const float* bv = (const float*)d_in[9];

  uint16_t* qws = (uint16_t*)d_ws;                       // [4][4096][256] bf16
  uint16_t* kws = qws + (size_t)4 * 4096 * 256;          // [4][4096][256] bf16
  uint16_t* vws = kws + (size_t)4 * 4096 * 256;          // [4][256][4096] bf16 (V^T)

  proj_kernel<<<dim3(128, 2, 3), 256, 0, stream>>>(
      xq, xk, xv, wq, wk, wv, bq, bk, bv, qws, kws, vws);

  (void)hipFuncSetAttribute((const void*)attn_kernel,
                            hipFuncAttributeMaxDynamicSharedMemorySize, 73728);
  attn_kernel<<<dim3(256), 512, 73728, stream>>>(qws, kws, vws, (float*)d_out);
}

// Round 6
// 434.985 us; speedup vs baseline: 1.4589x; 1.4589x over previous
//
#include <hip/hip_runtime.h>
#include <stdint.h>

#define DEV static __device__ __forceinline__

typedef __bf16 bf16x8 __attribute__((ext_vector_type(8)));
typedef float f32x4 __attribute__((ext_vector_type(4)));

typedef const __attribute__((address_space(1))) void* as1cp;
typedef __attribute__((address_space(3))) void* as3p;

DEV uint32_t pk2(float lo, float hi) {       // -> v_cvt_pk_bf16_f32 (RNE)
  uint16_t a = __builtin_bit_cast(uint16_t, (__bf16)lo);
  uint16_t b = __builtin_bit_cast(uint16_t, (__bf16)hi);
  return (uint32_t)a | ((uint32_t)b << 16);
}
DEV uint16_t bfc(float f) { return __builtin_bit_cast(uint16_t, (__bf16)f); }
DEV float bf2f(uint32_t h) { return __builtin_bit_cast(float, h << 16); }

DEV void gll16(const void* g, void* l) {
  __builtin_amdgcn_global_load_lds((as1cp)g, (as3p)l, 16, 0, 0);
}

// ---------------------------------------------------------------------------
// Projection v5: out = X @ W^T + b (M=16384, N=256, K=1024), bf16 MFMA.
// BM=128, BN=128, grid 128x2x3 = 768 blocks = 3 blocks/CU, 256 thr (4 waves).
// FIX vs R4: staging flat-index f=r*256+tid -> lanes read CONTIGUOUS 256B row
// segments (4 full rows per wave instruction) instead of scattered 16B pieces
// (was ~4x HBM read amplification). Conversions via native __bf16 casts.
// z=0 -> q (scaled log2(e)/16), z=1 -> k, z=2 -> v TRANSPOSED [b][d][s].
// ---------------------------------------------------------------------------
__global__ __launch_bounds__(256, 3) void proj_kernel(
    const float* __restrict__ xq, const float* __restrict__ xk, const float* __restrict__ xv,
    const float* __restrict__ wq, const float* __restrict__ wk, const float* __restrict__ wv,
    const float* __restrict__ bq, const float* __restrict__ bk, const float* __restrict__ bv,
    uint16_t* __restrict__ qo, uint16_t* __restrict__ ko, uint16_t* __restrict__ vo)
{
  const int z = blockIdx.z;
  const float* X  = (z == 0) ? xq : (z == 1) ? xk : xv;
  const float* W  = (z == 0) ? wq : (z == 1) ? wk : wv;
  const float* Bi = (z == 0) ? bq : (z == 1) ? bk : bv;

  const int tid = threadIdx.x;
  const int lane = tid & 63;
  const int w = tid >> 6;
  const int wm = w >> 1, wn = w & 1;
  const int l15 = lane & 15, g = lane >> 4;
  const int m0 = blockIdx.x * 128;
  const int n0 = blockIdx.y * 128;

  __shared__ uint16_t sA[128 * 64];   // 16 KB, 128B rows, XOR-swizzled
  __shared__ uint16_t sB[128 * 64];

  // staging: flat f = r*256+tid -> row = f>>4 (= r*16 + tid>>4), 16B-unit = f&15
  const int srow = tid >> 4;          // 0..15
  const int scu  = tid & 15;
  const float* Abase = X + (size_t)(m0 + srow) * 1024 + scu * 4;
  const float* Wbase = W + (size_t)(n0 + srow) * 1024 + scu * 4;
  uint32_t sdst[8];
  #pragma unroll
  for (int r = 0; r < 8; ++r) {
    uint32_t row = (uint32_t)(r * 16 + srow);
    sdst[r] = row * 128 + (((uint32_t)scu * 8) ^ ((row & 7) << 4));
  }

  f32x4 acc[4][4];
  #pragma unroll
  for (int i = 0; i < 4; ++i)
    #pragma unroll
    for (int j = 0; j < 4; ++j) { f32x4 zz = {0.f, 0.f, 0.f, 0.f}; acc[i][j] = zz; }

  float4 a4[8];
  #pragma unroll
  for (int r = 0; r < 8; ++r)
    a4[r] = *(const float4*)(Abase + (size_t)r * 16384);

  for (int kt = 0; kt < 16; ++kt) {
    if (kt) __syncthreads();            // previous tile fully consumed
    // stage A from prefetched regs (8B packed-bf16 writes)
    #pragma unroll
    for (int r = 0; r < 8; ++r) {
      uint2 p; p.x = pk2(a4[r].x, a4[r].y); p.y = pk2(a4[r].z, a4[r].w);
      *(uint2*)((char*)sA + sdst[r]) = p;
    }
    // load + stage W (L2-hot after first touches)
    {
      float4 w4[8];
      #pragma unroll
      for (int r = 0; r < 8; ++r)
        w4[r] = *(const float4*)(Wbase + (size_t)r * 16384 + kt * 64);
      #pragma unroll
      for (int r = 0; r < 8; ++r) {
        uint2 p; p.x = pk2(w4[r].x, w4[r].y); p.y = pk2(w4[r].z, w4[r].w);
        *(uint2*)((char*)sB + sdst[r]) = p;
      }
    }
    __syncthreads();                    // tile visible
    if (kt < 15) {                      // prefetch next A under MFMAs
      #pragma unroll
      for (int r = 0; r < 8; ++r)
        a4[r] = *(const float4*)(Abase + (size_t)r * 16384 + (kt + 1) * 64);
    }
    #pragma unroll
    for (int ks = 0; ks < 2; ++ks) {
      bf16x8 fa[4], fb[4];
      #pragma unroll
      for (int f = 0; f < 4; ++f) {
        uint32_t row = wm * 64 + 16 * f + l15;
        fa[f] = *(const bf16x8*)((char*)sA + row * 128 +
                 (((uint32_t)(ks * 64 + g * 16)) ^ ((row & 7) << 4)));
      }
      #pragma unroll
      for (int f = 0; f < 4; ++f) {
        uint32_t row = wn * 64 + 16 * f + l15;
        fb[f] = *(const bf16x8*)((char*)sB + row * 128 +
                 (((uint32_t)(ks * 64 + g * 16)) ^ ((row & 7) << 4)));
      }
      #pragma unroll
      for (int fm = 0; fm < 4; ++fm)
        #pragma unroll
        for (int fn = 0; fn < 4; ++fn)
          acc[fm][fn] = __builtin_amdgcn_mfma_f32_16x16x32_bf16(fa[fm], fb[fn], acc[fm][fn], 0, 0, 0);
    }
  }

  // epilogue: C row = m0+wm*64+16fm+4g+r, col = n0+wn*64+16fn+l15
  #pragma unroll
  for (int fn = 0; fn < 4; ++fn) {
    const int n = n0 + wn * 64 + 16 * fn + l15;
    const float bias = Bi[n];
    #pragma unroll
    for (int fm = 0; fm < 4; ++fm) {
      const int mg = m0 + wm * 64 + 16 * fm + 4 * g;
      if (z == 0) {
        #pragma unroll
        for (int r = 0; r < 4; ++r)
          qo[(size_t)(mg + r) * 256 + n] =
              bfc((acc[fm][fn][r] + bias) * 0.09016844f);   // log2(e)/16
      } else if (z == 1) {
        #pragma unroll
        for (int r = 0; r < 4; ++r)
          ko[(size_t)(mg + r) * 256 + n] = bfc(acc[fm][fn][r] + bias);
      } else {
        uint2 pv;
        pv.x = pk2(acc[fm][fn][0] + bias, acc[fm][fn][1] + bias);
        pv.y = pk2(acc[fm][fn][2] + bias, acc[fm][fn][3] + bias);
        *(uint2*)(vo + (((size_t)(mg >> 12)) << 20) + (((size_t)n) << 12) + (mg & 4095)) = pv;
      }
    }
  }
}

// ---------------------------------------------------------------------------
// Flash attention v6 = R4 structure (double-buffered, measured 191us, no
// spill) + R5's conflict-free V layout. 512 thr = 2 KV-halves x 4 q-waves,
// KVBLK=32 per half. LDS 136KB: K[h][buf] 4x16KB | V[h][buf] 4x16KB | P 8KB.
//   K [32 rows][512B], col-swizzled via pre-swizzled gll source;
//   V [fd 16][lane 64][16B]: PV frag read = Vb + fd*1024 + lane*16
//   (lane-linear, conflict-free).
// One barrier per tile: sync; STAGE(t+1, buf^1); compute(buf). Flash-merge.
// ---------------------------------------------------------------------------
__global__ __launch_bounds__(512) void attn_kernel(
    const uint16_t* __restrict__ qg, const uint16_t* __restrict__ kg,
    const uint16_t* __restrict__ vg, float* __restrict__ out)
{
  extern __shared__ char smem[];   // K:[0,64K) V:[64K,128K) P:[128K,136K)

  const int bid = blockIdx.x;
  const int xcd = bid & 7, slot = bid >> 3;
  const int batch = xcd >> 1;                       // batch pinned to XCD pair
  const int q0 = (((xcd & 1) << 5) + slot) * 64;

  const int tid = threadIdx.x;
  const int lane = tid & 63;
  const int w = tid >> 6;
  const int hv = w >> 2;                  // KV half
  const int wq = w & 3;                   // q sub-tile
  const int l15 = lane & 15, g = lane >> 4;
  const size_t rowb = (size_t)batch * 4096;

  bf16x8 qf[8];
  {
    const uint16_t* qp = qg + (rowb + q0 + wq * 16 + l15) * 256;
    #pragma unroll
    for (int ks = 0; ks < 8; ++ks) qf[ks] = *(const bf16x8*)(qp + ks * 32 + g * 8);
  }

  f32x4 o[16];
  #pragma unroll
  for (int i = 0; i < 16; ++i) { f32x4 zz = {0.f, 0.f, 0.f, 0.f}; o[i] = zz; }
  float mrow[4], lrow[4];
  #pragma unroll
  for (int r = 0; r < 4; ++r) { mrow[r] = -1e30f; lrow[r] = 0.f; }

  const char* kgb = (const char*)(kg + rowb * 256);                 // K [s][256]
  const char* vgb = (const char*)(vg + (size_t)batch * 256 * 4096); // V^T [d][4096]

  // staging offsets (constant per thread). Each thread: 2 slots x 2 halves
  // x {K,V}. K slot L: row=L>>9, col pre-swizzled. V slot L: fd=L>>10,
  // g2=(L>>8)&3, lv=(L>>4)&15 -> content V^T[fd*16+lv][kv0+8*g2..+8].
  uint32_t kOff[2][2], vOff[2][2], dOff[2];
  #pragma unroll
  for (int i = 0; i < 2; ++i) {
    uint32_t L = (uint32_t)(i * 512 + tid) * 16;
    dOff[i] = L;
    uint32_t row = L >> 9;
    uint32_t colsw = (L & 511) ^ ((row & 7) << 4);
    uint32_t fd = L >> 10, g2 = (L >> 8) & 3, lv = (L >> 4) & 15;
    #pragma unroll
    for (int h = 0; h < 2; ++h) {
      kOff[h][i] = (h * 32 + row) * 512 + colsw;
      vOff[h][i] = (fd * 16 + lv) * 8192 + (h * 32 + g2 * 8) * 2;
    }
  }

  auto STAGE = [&](int buf, int t) {
    const char* kt_ = kgb + (size_t)t * 32768;   // 64 kv rows * 512B
    const char* vt_ = vgb + (size_t)t * 128;     // 64 kv * 2B
    #pragma unroll
    for (int h = 0; h < 2; ++h) {
      char* kd = smem + (size_t)(h * 2 + buf) * 16384;
      char* vd = smem + 65536 + (size_t)(h * 2 + buf) * 16384;
      #pragma unroll
      for (int i = 0; i < 2; ++i) {
        gll16(kt_ + kOff[h][i], kd + dOff[i]);
        gll16(vt_ + vOff[h][i], vd + dOff[i]);
      }
    }
  };

  STAGE(0, 0);
  int buf = 0;
  const int hb = hv * 2;
  char* Pw = smem + 131072 + (size_t)w * 1024;

  for (int t = 0; t < 64; ++t) {
    __syncthreads();                     // stage(t) visible; buf^1 consumers done
    if (t + 1 < 64) STAGE(buf ^ 1, t + 1);   // next tile flies under compute

    const char* Kb = smem + (size_t)(hb + buf) * 16384;
    const char* Vb = smem + 65536 + (size_t)(hb + buf) * 16384;

    // ---- S = Q K^T : q-row = 4g+r, kv = 16f+l15
    f32x4 s4[2];
    #pragma unroll
    for (int f = 0; f < 2; ++f) { f32x4 zz = {0.f, 0.f, 0.f, 0.f}; s4[f] = zz; }
    #pragma unroll
    for (int ks = 0; ks < 8; ++ks) {
      bf16x8 kf[2];
      #pragma unroll
      for (int f = 0; f < 2; ++f) {
        uint32_t row = 16 * f + l15;
        kf[f] = *(const bf16x8*)(Kb + row * 512 +
                 (((uint32_t)(ks * 64 + g * 16)) ^ ((l15 & 7) << 4)));
      }
      #pragma unroll
      for (int f = 0; f < 2; ++f)
        s4[f] = __builtin_amdgcn_mfma_f32_16x16x32_bf16(qf[ks], kf[f], s4[f], 0, 0, 0);
    }

    // ---- online softmax (exp2 domain) + defer-max (T13, THR=8)
    float mx[4];
    #pragma unroll
    for (int r = 0; r < 4; ++r) {
      float m2 = fmaxf(s4[0][r], s4[1][r]);
      m2 = fmaxf(m2, __shfl_xor(m2, 1, 64));
      m2 = fmaxf(m2, __shfl_xor(m2, 2, 64));
      m2 = fmaxf(m2, __shfl_xor(m2, 4, 64));
      m2 = fmaxf(m2, __shfl_xor(m2, 8, 64));
      mx[r] = m2;
    }
    int stable = (mx[0] <= mrow[0] + 8.f) && (mx[1] <= mrow[1] + 8.f) &&
                 (mx[2] <= mrow[2] + 8.f) && (mx[3] <= mrow[3] + 8.f);
    if (!__all(stable)) {
      float sc[4];
      #pragma unroll
      for (int r = 0; r < 4; ++r) {
        float mn = fmaxf(mrow[r], mx[r]);
        sc[r] = exp2f(mrow[r] - mn);
        mrow[r] = mn;
        lrow[r] *= sc[r];
      }
      #pragma unroll
      for (int j = 0; j < 16; ++j)
        #pragma unroll
        for (int r = 0; r < 4; ++r) o[j][r] *= sc[r];
    }
    float ps[2][4];
    #pragma unroll
    for (int r = 0; r < 4; ++r) {
      float sum = 0.f;
      #pragma unroll
      for (int f = 0; f < 2; ++f) { ps[f][r] = exp2f(s4[f][r] - mrow[r]); sum += ps[f][r]; }
      sum += __shfl_xor(sum, 1, 64);
      sum += __shfl_xor(sum, 2, 64);
      sum += __shfl_xor(sum, 4, 64);
      sum += __shfl_xor(sum, 8, 64);
      lrow[r] += sum;
    }

    // ---- P -> per-wave LDS (row=4g+r, 64B rows, ^(g<<4): 2-way = free)
    #pragma unroll
    for (int f = 0; f < 2; ++f)
      #pragma unroll
      for (int r = 0; r < 4; ++r)
        *(uint16_t*)(Pw + (4 * g + r) * 64 +
            (((uint32_t)(32 * f + 2 * l15)) ^ ((uint32_t)g << 4))) = bfc(ps[f][r]);

    // ---- O += P V (V frag = lane-linear read, conflict-free)
    bf16x8 pa = *(const bf16x8*)(Pw + l15 * 64 + 16 * (g ^ (l15 >> 2)));
    #pragma unroll
    for (int fd = 0; fd < 16; ++fd) {
      bf16x8 vbf = *(const bf16x8*)(Vb + fd * 1024 + lane * 16);
      o[fd] = __builtin_amdgcn_mfma_f32_16x16x32_bf16(pa, vbf, o[fd], 0, 0, 0);
    }

    buf ^= 1;
  }

  // ---- merge the two KV halves (flash combine); aliases K region (dead)
  float*    mlb = (float*)smem;             // [2][4][64][4] = 8 KB
  uint32_t* ob  = (uint32_t*)(smem + 8192); // [4][32][64]   = 32 KB
  __syncthreads();                          // all compute done before aliasing
  if (hv == 1) {
    #pragma unroll
    for (int r = 0; r < 4; ++r) {
      mlb[((0 * 4 + wq) * 64 + lane) * 4 + r] = mrow[r];
      mlb[((1 * 4 + wq) * 64 + lane) * 4 + r] = lrow[r];
    }
    #pragma unroll
    for (int fd = 0; fd < 16; ++fd)
      #pragma unroll
      for (int p = 0; p < 2; ++p)
        ob[(wq * 32 + fd * 2 + p) * 64 + lane] = pk2(o[fd][2 * p], o[fd][2 * p + 1]);
  }
  __syncthreads();
  if (hv == 0) {
    float a[4], b2[4], inv[4];
    #pragma unroll
    for (int r = 0; r < 4; ++r) {
      float mu = mlb[((0 * 4 + wq) * 64 + lane) * 4 + r];
      float lu = mlb[((1 * 4 + wq) * 64 + lane) * 4 + r];
      float mn = fmaxf(mrow[r], mu);
      a[r]  = exp2f(mrow[r] - mn);
      b2[r] = exp2f(mu - mn);
      inv[r] = 1.f / (lrow[r] * a[r] + lu * b2[r]);
    }
    float* op = out + (rowb + q0 + wq * 16) * 256;
    #pragma unroll
    for (int fd = 0; fd < 16; ++fd) {
      #pragma unroll
      for (int p = 0; p < 2; ++p) {
        uint32_t u = ob[(wq * 32 + fd * 2 + p) * 64 + lane];
        float vlo = bf2f(u & 0xffffu), vhi = bf2f(u >> 16);
        int r0 = 2 * p, r1 = 2 * p + 1;
        op[(4 * g + r0) * 256 + 16 * fd + l15] =
            (o[fd][r0] * a[r0] + vlo * b2[r0]) * inv[r0];
        op[(4 * g + r1) * 256 + 16 * fd + l15] =
            (o[fd][r1] * a[r1] + vhi * b2[r1]) * inv[r1];
      }
    }
  }
}

// ---------------------------------------------------------------------------
extern "C" void kernel_launch(void* const* d_in, const int* in_sizes, int n_in,
                              void* d_out, int out_size, void* d_ws, size_t ws_size,
                              hipStream_t stream) {
  const float* xq = (const float*)d_in[0];
  const float* xk = (const float*)d_in[1];
  const float* xv = (const float*)d_in[2];
  // d_in[3] = mask (unused by reference forward)
  const float* wq = (const float*)d_in[4];
  const float* bq = (const float*)d_in[5];
  const float* wk = (const float*)d_in[6];
  const float* bk = (const float*)d_in[7];
  const float* wv = (const float*)d_in[8];
  const float* bv = (const float*)d_in[9];

  uint16_t* qws = (uint16_t*)d_ws;                       // [4][4096][256] bf16
  uint16_t* kws = qws + (size_t)4 * 4096 * 256;          // [4][4096][256] bf16
  uint16_t* vws = kws + (size_t)4 * 4096 * 256;          // [4][256][4096] bf16 (V^T)

  proj_kernel<<<dim3(128, 2, 3), 256, 0, stream>>>(
      xq, xk, xv, wq, wk, wv, bq, bk, bv, qws, kws, vws);

  (void)hipFuncSetAttribute((const void*)attn_kernel,
                            hipFuncAttributeMaxDynamicSharedMemorySize, 139264);
  attn_kernel<<<dim3(256), 512, 139264, stream>>>(qws, kws, vws, (float*)d_out);
}